// Round 10
// baseline (46.415 us; speedup 1.0000x reference)
//
#include <hip/hip_runtime.h>

// Problem constants (from reference): B=32, S=3, T=1000, F=257
#define BATCH   32
#define NSRC    3
#define TF      257000               // T*F
#define N4      (TF / 4)             // 64250 float4 groups per (b,s) slice
#define CHUNKS  32                   // blocks per batch -> 1024 blocks
#define THREADS 256
#define SPAN    (8 * THREADS)        // 2048 float4 (32 KB) contiguous per stream per block
#define NBLOCKS (BATCH * CHUNKS)     // 1024

typedef float f4 __attribute__((ext_vector_type(4)));

// Accumulate one batch of 6 float4 (inline, compile-time indices only --
// NO array-typed helper params: that defeated SROA in R3 and spilled).
#define ACC6(Aj, Tk)                                                      \
    do {                                                                  \
        _Pragma("unroll")                                                 \
        for (int j = 0; j < NSRC; ++j)                                    \
            _Pragma("unroll")                                             \
            for (int k = 0; k < NSRC; ++k) {                              \
                acc[j][k] += fabsf(Aj[j].x - Tk[k].x)                     \
                           + fabsf(Aj[j].y - Tk[k].y)                     \
                           + fabsf(Aj[j].z - Tk[k].z)                     \
                           + fabsf(Aj[j].w - Tk[k].w);                    \
            }                                                             \
    } while (0)

// One round = 12 up-front loads (2 iters x 6 streams) + 2x ACC6.
// R7-proven shape: VGPR=64, 8 waves/SIMD, no spill.
#define ROUND2(base_u)                                                    \
    do {                                                                  \
        f4 A[2][NSRC], T[2][NSRC];                                        \
        _Pragma("unroll")                                                 \
        for (int u = 0; u < 2; ++u) {                                     \
            const int i = i0 + (base_u + u) * THREADS;                    \
            _Pragma("unroll")                                             \
            for (int s = 0; s < NSRC; ++s) {                              \
                A[u][s] = pr[s][i]; T[u][s] = tg[s][i];                   \
            }                                                             \
        }                                                                 \
        ACC6(A[0], T[0]);                                                 \
        ACC6(A[1], T[1]);                                                 \
    } while (0)

// Kernel 1: per-block pairwise partial sums. Each block reads a CONTIGUOUS
// 2048-float4 (32 KB) range of each of the 6 streams, 8 iterations/thread,
// 1024 blocks (4 blocks/CU x 4 waves = 16 waves/CU). Half the per-block
// epilogue overhead of R7, double the DRAM burst length.
__global__ __launch_bounds__(THREADS) void pairwise_kernel(
    const float* __restrict__ pred,
    const float* __restrict__ tgt,
    float* __restrict__ partial)
{
    const int b     = blockIdx.x >> 5;    // / CHUNKS
    const int chunk = blockIdx.x & 31;    // % CHUNKS

    const f4* __restrict__ pr[NSRC];
    const f4* __restrict__ tg[NSRC];
#pragma unroll
    for (int s = 0; s < NSRC; ++s) {
        pr[s] = reinterpret_cast<const f4*>(pred + (size_t)(b * NSRC + s) * TF);
        tg[s] = reinterpret_cast<const f4*>(tgt  + (size_t)(b * NSRC + s) * TF);
    }

    const int i0 = chunk * SPAN + threadIdx.x;   // contiguous block range

    float acc[NSRC][NSRC];
#pragma unroll
    for (int j = 0; j < NSRC; ++j)
#pragma unroll
        for (int k = 0; k < NSRC; ++k) acc[j][k] = 0.0f;

    if (chunk < 31) {
        // Full 8 iterations guaranteed:
        // max i = 30*2048 + 7*256 + 255 = 63487 < 64250.
        ROUND2(0);
        ROUND2(2);
        ROUND2(4);
        ROUND2(6);
    } else {
        // Tail chunk 31: indices 63488..65535, valid up to 64249.
#pragma unroll
        for (int u = 0; u < 8; ++u) {
            const int i = i0 + u * THREADS;
            if (i < N4) {
                f4 a[NSRC], t[NSRC];
#pragma unroll
                for (int s = 0; s < NSRC; ++s) { a[s] = pr[s][i]; t[s] = tg[s][i]; }
                ACC6(a, t);
            }
        }
    }

    // Wave shuffle-reduce, cross-wave LDS reduce, one 9-float block store.
    __shared__ float red[THREADS / 64][9];
    const int wave = threadIdx.x >> 6;
    const int lane = threadIdx.x & 63;

#pragma unroll
    for (int j = 0; j < NSRC; ++j)
#pragma unroll
        for (int k = 0; k < NSRC; ++k) {
            float v = acc[j][k];
#pragma unroll
            for (int off = 32; off > 0; off >>= 1) v += __shfl_down(v, off);
            if (lane == 0) red[wave][j * 3 + k] = v;
        }
    __syncthreads();

    if (threadIdx.x < 9) {
        float v = red[0][threadIdx.x] + red[1][threadIdx.x]
                + red[2][threadIdx.x] + red[3][threadIdx.x];
        partial[(size_t)blockIdx.x * 9 + threadIdx.x] = v;   // [1024][9]
    }
}

// Kernel 2: reduce the 1024x9 partials, per-batch 6-perm argmin, mean.
// (R7-proven structure, adapted to 32 chunks: thread (b,g) sums 4 chunks.)
// out[0] = mean_b min_loss[b]; out[1 + b*3 + s] = (float)best_perm[b][s]
__global__ __launch_bounds__(256) void finalize_kernel(
    const float* __restrict__ partial,
    float* __restrict__ out)
{
    __shared__ float red2[BATCH][8][9];        // 9216 B
    const int t = threadIdx.x;                 // 0..255
    const int b = t >> 3;                      // 0..31
    const int g = t & 7;                       // 0..7 (8 groups of 4 chunks)

    float s[9];
#pragma unroll
    for (int p = 0; p < 9; ++p) s[p] = 0.0f;

    const float* base = partial + (size_t)(b * CHUNKS + g * 4) * 9;
#pragma unroll
    for (int c = 0; c < 4; ++c)
#pragma unroll
        for (int p = 0; p < 9; ++p) s[p] += base[c * 9 + p];

#pragma unroll
    for (int p = 0; p < 9; ++p) red2[b][g][p] = s[p];
    __syncthreads();

    if (t < BATCH) {
        const int bb = t;
        float m[9];
#pragma unroll
        for (int p = 0; p < 9; ++p) {
            float v = 0.0f;
#pragma unroll
            for (int gg = 0; gg < 8; ++gg) v += red2[bb][gg][p];
            m[p] = v * (1.0f / (float)TF);
        }

        const int perms[6][3] = {
            {0,1,2},{0,2,1},{1,0,2},{1,2,0},{2,0,1},{2,1,0}
        };
        float best = 3.402823e38f;
        int   bi   = 0;
#pragma unroll
        for (int p = 0; p < 6; ++p) {
            float l = (m[perms[p][0] * 3 + 0]
                     + m[perms[p][1] * 3 + 1]
                     + m[perms[p][2] * 3 + 2]) * (1.0f / 3.0f);
            if (l < best) { best = l; bi = p; }   // first-occurrence argmin
        }
        out[1 + bb * 3 + 0] = (float)perms[bi][0];
        out[1 + bb * 3 + 1] = (float)perms[bi][1];
        out[1 + bb * 3 + 2] = (float)perms[bi][2];

        // mean of best over lanes 0..31 (single wave)
        float minv = best;
#pragma unroll
        for (int off = 16; off > 0; off >>= 1) minv += __shfl_down(minv, off);
        if (t == 0) out[0] = minv * (1.0f / (float)BATCH);
    }
}

extern "C" void kernel_launch(void* const* d_in, const int* in_sizes, int n_in,
                              void* d_out, int out_size, void* d_ws, size_t ws_size,
                              hipStream_t stream)
{
    const float* pred = (const float*)d_in[0];
    const float* tgt  = (const float*)d_in[1];
    float* out     = (float*)d_out;
    float* partial = (float*)d_ws;   // [1024][9] floats, fully rewritten
                                     // every call (no zeroing needed)

    pairwise_kernel<<<NBLOCKS, THREADS, 0, stream>>>(pred, tgt, partial);
    finalize_kernel<<<1, 256, 0, stream>>>(partial, out);
}

// Round 11
// 39.607 us; speedup vs baseline: 1.1719x; 1.1719x over previous
//
#include <hip/hip_runtime.h>

// Problem constants (from reference): B=32, S=3, T=1000, F=257
#define BATCH   32
#define NSRC    3
#define TF      257000               // T*F
#define N4      (TF / 4)             // 64250 float4 groups per (b,s) slice
#define CHUNKS  64                   // blocks per batch -> 2048 blocks (1 residency gen)
#define THREADS 256
#define SPAN    (4 * THREADS)        // 1024 float4 contiguous per stream per block
#define NBLOCKS (BATCH * CHUNKS)     // 2048

typedef float f4 __attribute__((ext_vector_type(4)));

// Accumulate one batch of 6 float4 (inline, compile-time indices only --
// NO array-typed helper params: that defeated SROA in R3 and spilled).
// (R10 lesson: also no per-round scoped arrays -- two live rounds pushed
// VGPR to 132 and occupancy to 10%. This exact single-A/T-buffer shape
// is the proven VGPR=64 / 8-waves-per-SIMD envelope.)
#define ACC6(Aj, Tk)                                                      \
    do {                                                                  \
        _Pragma("unroll")                                                 \
        for (int j = 0; j < NSRC; ++j)                                    \
            _Pragma("unroll")                                             \
            for (int k = 0; k < NSRC; ++k) {                              \
                acc[j][k] += fabsf(Aj[j].x - Tk[k].x)                     \
                           + fabsf(Aj[j].y - Tk[k].y)                     \
                           + fabsf(Aj[j].z - Tk[k].z)                     \
                           + fabsf(Aj[j].w - Tk[k].w);                    \
            }                                                             \
    } while (0)

// Kernel 1: per-block pairwise partial sums. Each block reads a CONTIGUOUS
// 1024-float4 (16 KB) range of each of the 6 streams, 4 iterations/thread,
// single full-residency generation (2048 blocks x 4 waves = 8192 waves).
// R7-proven body: VGPR=64, no spill, ~5.65 TB/s effective fabric read.
__global__ __launch_bounds__(THREADS) void pairwise_kernel(
    const float* __restrict__ pred,
    const float* __restrict__ tgt,
    float* __restrict__ partial)
{
    const int b     = blockIdx.x >> 6;    // / CHUNKS
    const int chunk = blockIdx.x & 63;    // % CHUNKS

    const f4* __restrict__ pr[NSRC];
    const f4* __restrict__ tg[NSRC];
#pragma unroll
    for (int s = 0; s < NSRC; ++s) {
        pr[s] = reinterpret_cast<const f4*>(pred + (size_t)(b * NSRC + s) * TF);
        tg[s] = reinterpret_cast<const f4*>(tgt  + (size_t)(b * NSRC + s) * TF);
    }

    const int i0 = chunk * SPAN + threadIdx.x;   // contiguous block range

    float acc[NSRC][NSRC];
#pragma unroll
    for (int j = 0; j < NSRC; ++j)
#pragma unroll
        for (int k = 0; k < NSRC; ++k) acc[j][k] = 0.0f;

    if (chunk < 62) {
        // Full 4 iterations guaranteed:
        // max i = 61*1024 + 3*256 + 255 = 63487 < 64250.
        f4 A[2][NSRC], T[2][NSRC];
#pragma unroll
        for (int u = 0; u < 2; ++u) {
            const int i = i0 + u * THREADS;
#pragma unroll
            for (int s = 0; s < NSRC; ++s) { A[u][s] = pr[s][i]; T[u][s] = tg[s][i]; }
        }
        ACC6(A[0], T[0]);
        ACC6(A[1], T[1]);
#pragma unroll
        for (int u = 0; u < 2; ++u) {
            const int i = i0 + (2 + u) * THREADS;
#pragma unroll
            for (int s = 0; s < NSRC; ++s) { A[u][s] = pr[s][i]; T[u][s] = tg[s][i]; }
        }
        ACC6(A[0], T[0]);
        ACC6(A[1], T[1]);
    } else {
        // Tail: chunk 62 partial (63488..64249), chunk 63 idle (zeros).
#pragma unroll
        for (int u = 0; u < 4; ++u) {
            const int i = i0 + u * THREADS;
            if (i < N4) {
                f4 a[NSRC], t[NSRC];
#pragma unroll
                for (int s = 0; s < NSRC; ++s) { a[s] = pr[s][i]; t[s] = tg[s][i]; }
                ACC6(a, t);
            }
        }
    }

    // Wave shuffle-reduce, cross-wave LDS reduce, one 9-float block store.
    __shared__ float red[THREADS / 64][9];
    const int wave = threadIdx.x >> 6;
    const int lane = threadIdx.x & 63;

#pragma unroll
    for (int j = 0; j < NSRC; ++j)
#pragma unroll
        for (int k = 0; k < NSRC; ++k) {
            float v = acc[j][k];
#pragma unroll
            for (int off = 32; off > 0; off >>= 1) v += __shfl_down(v, off);
            if (lane == 0) red[wave][j * 3 + k] = v;
        }
    __syncthreads();

    if (threadIdx.x < 9) {
        float v = red[0][threadIdx.x] + red[1][threadIdx.x]
                + red[2][threadIdx.x] + red[3][threadIdx.x];
        partial[(size_t)blockIdx.x * 9 + threadIdx.x] = v;   // [2048][9]
    }
}

// Kernel 2: reduce the 2048x9 partials, per-batch 6-perm argmin, mean.
// out[0] = mean_b min_loss[b]; out[1 + b*3 + s] = (float)best_perm[b][s]
__global__ __launch_bounds__(256) void finalize_kernel(
    const float* __restrict__ partial,
    float* __restrict__ out)
{
    __shared__ float red2[BATCH][8][9];        // 9216 B
    const int t = threadIdx.x;                 // 0..255
    const int b = t >> 3;                      // 0..31
    const int g = t & 7;                       // 0..7 (8 groups of 8 chunks)

    float s[9];
#pragma unroll
    for (int p = 0; p < 9; ++p) s[p] = 0.0f;

    const float* base = partial + (size_t)(b * CHUNKS + g * 8) * 9;
#pragma unroll
    for (int c = 0; c < 8; ++c)
#pragma unroll
        for (int p = 0; p < 9; ++p) s[p] += base[c * 9 + p];

#pragma unroll
    for (int p = 0; p < 9; ++p) red2[b][g][p] = s[p];
    __syncthreads();

    if (t < BATCH) {
        const int bb = t;
        float m[9];
#pragma unroll
        for (int p = 0; p < 9; ++p) {
            float v = 0.0f;
#pragma unroll
            for (int gg = 0; gg < 8; ++gg) v += red2[bb][gg][p];
            m[p] = v * (1.0f / (float)TF);
        }

        const int perms[6][3] = {
            {0,1,2},{0,2,1},{1,0,2},{1,2,0},{2,0,1},{2,1,0}
        };
        float best = 3.402823e38f;
        int   bi   = 0;
#pragma unroll
        for (int p = 0; p < 6; ++p) {
            float l = (m[perms[p][0] * 3 + 0]
                     + m[perms[p][1] * 3 + 1]
                     + m[perms[p][2] * 3 + 2]) * (1.0f / 3.0f);
            if (l < best) { best = l; bi = p; }   // first-occurrence argmin
        }
        out[1 + bb * 3 + 0] = (float)perms[bi][0];
        out[1 + bb * 3 + 1] = (float)perms[bi][1];
        out[1 + bb * 3 + 2] = (float)perms[bi][2];

        // mean of best over lanes 0..31 (single wave)
        float minv = best;
#pragma unroll
        for (int off = 16; off > 0; off >>= 1) minv += __shfl_down(minv, off);
        if (t == 0) out[0] = minv * (1.0f / (float)BATCH);
    }
}

extern "C" void kernel_launch(void* const* d_in, const int* in_sizes, int n_in,
                              void* d_out, int out_size, void* d_ws, size_t ws_size,
                              hipStream_t stream)
{
    const float* pred = (const float*)d_in[0];
    const float* tgt  = (const float*)d_in[1];
    float* out     = (float*)d_out;
    float* partial = (float*)d_ws;   // [2048][9] floats, fully rewritten
                                     // every call (no zeroing needed)

    pairwise_kernel<<<NBLOCKS, THREADS, 0, stream>>>(pred, tgt, partial);
    finalize_kernel<<<1, 256, 0, stream>>>(partial, out);
}